// Round 5
// baseline (633.617 us; speedup 1.0000x reference)
//
#include <hip/hip_runtime.h>

#define LN_EPS 1e-5f

typedef unsigned short ushortT;

__device__ __forceinline__ float4 ld4(const float* p) { return *reinterpret_cast<const float4*>(p); }
__device__ __forceinline__ void st4(float* p, float4 v) { *reinterpret_cast<float4*>(p) = v; }
__device__ __forceinline__ float bf2f(unsigned u) { return __uint_as_float(u << 16); }
__device__ __forceinline__ unsigned short f2bf(float f) {
    unsigned u = __float_as_uint(f);
    u += 0x7fffu + ((u >> 16) & 1u);   // round to nearest even
    return (unsigned short)(u >> 16);
}
__device__ __forceinline__ unsigned pack2(float a, float b) {
    return (unsigned)f2bf(a) | ((unsigned)f2bf(b) << 16);
}

// ---------------- CSR build ----------------

__global__ __launch_bounds__(256) void k_zero_i32(int* __restrict__ p, int n) {
    int i = blockIdx.x * 256 + threadIdx.x;
    if (i < n) p[i] = 0;
}

__global__ __launch_bounds__(256) void k_count(const int* __restrict__ dst, int* __restrict__ counts, int E) {
    int i = blockIdx.x * 256 + threadIdx.x;
    if (i < E) atomicAdd(&counts[dst[i]], 1);
}

__global__ __launch_bounds__(256) void k_dinv(const int* __restrict__ counts, float* __restrict__ dinv, int n) {
    int i = blockIdx.x * 256 + threadIdx.x;
    if (i < n) dinv[i] = rsqrtf((float)(counts[i] + 1));   // +1 = self loop
}

__global__ __launch_bounds__(512) void k_scan1(const int* __restrict__ counts, int* __restrict__ bsum, int n) {
    __shared__ int s[512];
    int idx = blockIdx.x * 512 + threadIdx.x;
    s[threadIdx.x] = (idx < n) ? counts[idx] : 0;
    __syncthreads();
    for (int d = 256; d > 0; d >>= 1) {
        if (threadIdx.x < d) s[threadIdx.x] += s[threadIdx.x + d];
        __syncthreads();
    }
    if (threadIdx.x == 0) bsum[blockIdx.x] = s[0];
}

// parallel single-block exclusive scan over block sums (nb <= 512)
__global__ __launch_bounds__(512) void k_scan2(int* __restrict__ bsum, int nb) {
    __shared__ int s[512];
    int t = threadIdx.x;
    int v = (t < nb) ? bsum[t] : 0;
    s[t] = v;
    __syncthreads();
    for (int d = 1; d < 512; d <<= 1) {
        int tv = (t >= d) ? s[t - d] : 0;
        __syncthreads();
        s[t] += tv;
        __syncthreads();
    }
    if (t < nb) bsum[t] = s[t] - v;   // exclusive
}

__global__ __launch_bounds__(512) void k_scan3(const int* __restrict__ counts, const int* __restrict__ bsum,
                                               int* __restrict__ offsets, int* __restrict__ cursor, int n) {
    __shared__ int s[512];
    int tid = threadIdx.x;
    int idx = blockIdx.x * 512 + tid;
    int v = (idx < n) ? counts[idx] : 0;
    s[tid] = v;
    __syncthreads();
    for (int d = 1; d < 512; d <<= 1) {
        int t = (tid >= d) ? s[tid - d] : 0;
        __syncthreads();
        s[tid] += t;
        __syncthreads();
    }
    if (idx < n) {
        int ex = s[tid] - v + bsum[blockIdx.x];
        offsets[idx] = ex;
        cursor[idx] = ex;
    }
}

// one fused 8B scattered store per edge: {src, bits(dinv[src])}
__global__ __launch_bounds__(256) void k_fill(const int* __restrict__ src, const int* __restrict__ dst,
                                              const float* __restrict__ dinv, int* __restrict__ cursor,
                                              uint2* __restrict__ csr, int E) {
    int i = blockIdx.x * 256 + threadIdx.x;
    if (i < E) {
        int d = dst[i], s = src[i];
        int p = atomicAdd(&cursor[d], 1);
        uint2 v;
        v.x = (unsigned)s;
        v.y = __float_as_uint(dinv[s]);
        csr[p] = v;
    }
}

// ---------------- f32 -> bf16 convert ----------------

__global__ __launch_bounds__(256) void k_cvt_bf16(const float* __restrict__ in, ushortT* __restrict__ o, int n4) {
    int i = blockIdx.x * 256 + threadIdx.x;
    if (i < n4) {
        float4 v = ld4(in + (size_t)i * 4);
        uint2 pk;
        pk.x = pack2(v.x, v.y);
        pk.y = pack2(v.z, v.w);
        *reinterpret_cast<uint2*>(o + (size_t)i * 4) = pk;
    }
}

// ---------------- fused: LDS-aggregate -> GEMM -> bias/LN/ReLU/skip ----------------
// Phase A: G=K/8 lanes per node gather bf16 rows, accumulate f32, write LDS Xl.
// Phase B: Xl[NODES][K] @ W[K][128] with LN epilogue.

template <int K>
__global__ __launch_bounds__(256) void k_agg_gemm_ln(
        const ushortT* __restrict__ t16, const uint2* __restrict__ csr,
        const int* __restrict__ rs, const int* __restrict__ re,
        const float* __restrict__ dinv,
        const float* __restrict__ W, const float* __restrict__ bias,
        const float* __restrict__ g, const float* __restrict__ be,
        const float* __restrict__ skip,
        float* __restrict__ out32, ushortT* __restrict__ out16, int n) {
    constexpr int M = 128;
    constexpr int G = K / 8;          // lanes per node (agg phase)
    constexpr int NODES = 256 / G;    // 32 (K=64) / 16 (K=128)
    constexpr int RPT = NODES / 8;    // 4 / 2
    constexpr int KP = K + 8;         // row pad keeps 16B alignment

    __shared__ float Wl[64][M];
    __shared__ float Xl[NODES][KP];

    const int tid = threadIdx.x;

    // ---- Phase A: aggregate into LDS ----
    {
        const int grp = tid / G;
        const int sub = tid % G;
        const int node = blockIdx.x * NODES + grp;
        float a[8];
#pragma unroll
        for (int i = 0; i < 8; ++i) a[i] = 0.f;

        if (node < n) {
            const float di = dinv[node];
            const ushortT* base = t16 + sub * 8;
            const int p0 = rs[node], p1 = re[node];

            auto acc8 = [&](uint4 v, float w) {
                a[0] = fmaf(bf2f(v.x & 0xffffu), w, a[0]); a[1] = fmaf(bf2f(v.x >> 16), w, a[1]);
                a[2] = fmaf(bf2f(v.y & 0xffffu), w, a[2]); a[3] = fmaf(bf2f(v.y >> 16), w, a[3]);
                a[4] = fmaf(bf2f(v.z & 0xffffu), w, a[4]); a[5] = fmaf(bf2f(v.z >> 16), w, a[5]);
                a[6] = fmaf(bf2f(v.w & 0xffffu), w, a[6]); a[7] = fmaf(bf2f(v.w >> 16), w, a[7]);
            };

            int p = p0;
            for (; p + 2 <= p1; p += 2) {
                uint2 e0 = csr[p], e1 = csr[p + 1];
                float w0 = __uint_as_float(e0.y) * di;
                float w1 = __uint_as_float(e1.y) * di;
                uint4 v0 = *reinterpret_cast<const uint4*>(base + (size_t)e0.x * K);
                uint4 v1 = *reinterpret_cast<const uint4*>(base + (size_t)e1.x * K);
                acc8(v0, w0);
                acc8(v1, w1);
            }
            if (p < p1) {
                uint2 e0 = csr[p];
                float w0 = __uint_as_float(e0.y) * di;
                uint4 v0 = *reinterpret_cast<const uint4*>(base + (size_t)e0.x * K);
                acc8(v0, w0);
            }
            {   // self loop
                uint4 v = *reinterpret_cast<const uint4*>(base + (size_t)node * K);
                acc8(v, di * di);
            }
        }
        st4(&Xl[grp][sub * 8], make_float4(a[0], a[1], a[2], a[3]));
        st4(&Xl[grp][sub * 8 + 4], make_float4(a[4], a[5], a[6], a[7]));
    }

    // ---- Phase B: GEMM + LN epilogue ----
    const int cg = tid & 31;
    const int rg = tid >> 5;
    const float4 bias4 = ld4(bias + cg * 4);
    const float4 g4 = ld4(g + cg * 4);
    const float4 be4 = ld4(be + cg * 4);

    float4 acc[RPT];
#pragma unroll
    for (int r = 0; r < RPT; ++r) acc[r] = bias4;

    for (int kh = 0; kh < K; kh += 64) {
        __syncthreads();   // Xl ready (1st iter) / Wl reuse safe (later)
        for (int i = tid; i < 64 * M / 4; i += 256) {
            int kk = i / (M / 4), c = i % (M / 4);
            st4(&Wl[kk][c * 4], ld4(W + (size_t)(kh + kk) * M + c * 4));
        }
        __syncthreads();
#pragma unroll 4
        for (int kk = 0; kk < 64; ++kk) {
            float4 w4 = ld4(&Wl[kk][cg * 4]);
#pragma unroll
            for (int r = 0; r < RPT; ++r) {
                float xv = Xl[rg * RPT + r][kh + kk];
                acc[r].x = fmaf(xv, w4.x, acc[r].x);
                acc[r].y = fmaf(xv, w4.y, acc[r].y);
                acc[r].z = fmaf(xv, w4.z, acc[r].z);
                acc[r].w = fmaf(xv, w4.w, acc[r].w);
            }
        }
    }

#pragma unroll
    for (int r = 0; r < RPT; ++r) {
        int gr = blockIdx.x * NODES + rg * RPT + r;
        if (gr >= n) continue;
        float4 a = acc[r];
        float sum = a.x + a.y + a.z + a.w;
#pragma unroll
        for (int m = 16; m > 0; m >>= 1) sum += __shfl_xor(sum, m, 32);
        const float mean = sum * (1.f / 128.f);
        float dx = a.x - mean, dy = a.y - mean, dz = a.z - mean, dw = a.w - mean;
        float sq = dx * dx + dy * dy + dz * dz + dw * dw;
#pragma unroll
        for (int m = 16; m > 0; m >>= 1) sq += __shfl_xor(sq, m, 32);
        const float rstd = rsqrtf(sq * (1.f / 128.f) + LN_EPS);
        float4 s4 = ld4(skip + (size_t)gr * 128 + cg * 4);
        float4 y;
        y.x = fmaxf(fmaf(dx * rstd, g4.x, be4.x), 0.f) + s4.x;
        y.y = fmaxf(fmaf(dy * rstd, g4.y, be4.y), 0.f) + s4.y;
        y.z = fmaxf(fmaf(dz * rstd, g4.z, be4.z), 0.f) + s4.z;
        y.w = fmaxf(fmaf(dw * rstd, g4.w, be4.w), 0.f) + s4.w;
        st4(out32 + (size_t)gr * 128 + cg * 4, y);
        if (out16) {
            uint2 pk;
            pk.x = pack2(y.x, y.y);
            pk.y = pack2(y.z, y.w);
            *reinterpret_cast<uint2*>(out16 + (size_t)gr * 128 + cg * 4) = pk;
        }
    }
}

// ---------------- final: out += Agg(hw3_16) + b3 (out pre-filled with skip3) ----------------

__global__ __launch_bounds__(256) void k_final(const ushortT* __restrict__ t16,
                                               const int* __restrict__ rs, const int* __restrict__ re,
                                               const uint2* __restrict__ csr,
                                               const float* __restrict__ dinv, const float* __restrict__ bias,
                                               float* __restrict__ out, int n) {
    constexpr int C = 64, G = 8, NPB = 32;
    const int grp = threadIdx.x / G;
    const int sub = threadIdx.x % G;
    const int node = blockIdx.x * NPB + grp;
    if (node >= n) return;
    const float di = dinv[node];
    float a[8];
#pragma unroll
    for (int i = 0; i < 8; ++i) a[i] = 0.f;
    const ushortT* base = t16 + sub * 8;
    const int p0 = rs[node], p1 = re[node];

    auto acc8 = [&](uint4 v, float w) {
        a[0] = fmaf(bf2f(v.x & 0xffffu), w, a[0]); a[1] = fmaf(bf2f(v.x >> 16), w, a[1]);
        a[2] = fmaf(bf2f(v.y & 0xffffu), w, a[2]); a[3] = fmaf(bf2f(v.y >> 16), w, a[3]);
        a[4] = fmaf(bf2f(v.z & 0xffffu), w, a[4]); a[5] = fmaf(bf2f(v.z >> 16), w, a[5]);
        a[6] = fmaf(bf2f(v.w & 0xffffu), w, a[6]); a[7] = fmaf(bf2f(v.w >> 16), w, a[7]);
    };

    int p = p0;
    for (; p + 2 <= p1; p += 2) {
        uint2 e0 = csr[p], e1 = csr[p + 1];
        float w0 = __uint_as_float(e0.y) * di;
        float w1 = __uint_as_float(e1.y) * di;
        uint4 v0 = *reinterpret_cast<const uint4*>(base + (size_t)e0.x * C);
        uint4 v1 = *reinterpret_cast<const uint4*>(base + (size_t)e1.x * C);
        acc8(v0, w0);
        acc8(v1, w1);
    }
    if (p < p1) {
        uint2 e0 = csr[p];
        float w0 = __uint_as_float(e0.y) * di;
        uint4 v0 = *reinterpret_cast<const uint4*>(base + (size_t)e0.x * C);
        acc8(v0, w0);
    }
    {
        uint4 v = *reinterpret_cast<const uint4*>(base + (size_t)node * C);
        acc8(v, di * di);
    }
    float* o = out + (size_t)node * 64 + sub * 8;
    const float* b = bias + sub * 8;
    float4 c0 = ld4(o), c1 = ld4(o + 4);
    float4 b0 = ld4(b), b1 = ld4(b + 4);
    st4(o, make_float4(c0.x + a[0] + b0.x, c0.y + a[1] + b0.y,
                       c0.z + a[2] + b0.z, c0.w + a[3] + b0.w));
    st4(o + 4, make_float4(c1.x + a[4] + b1.x, c1.y + a[5] + b1.y,
                           c1.z + a[6] + b1.z, c1.w + a[7] + b1.w));
}

// ---------------- small-K GEMM: out[N,M] = in[N,K] @ W[K,M] (+bias); f32 or bf16 out ----------------

template <int K, int M, bool BF16OUT>
__global__ __launch_bounds__(256) void gemm_small(const float* __restrict__ in, const float* __restrict__ W,
                                                  const float* __restrict__ bias, void* __restrict__ outp,
                                                  int nrows) {
    constexpr int CG = M / 4;
    constexpr int RG = 256 / CG;
    constexpr int RPT = 4;
    constexpr int ROWS = RG * RPT;
    constexpr int KH = 64;
    constexpr int KP = K + 4;

    __shared__ float Wl[KH][M];
    __shared__ float Xl[ROWS][KP];

    const int tid = threadIdx.x;
    const int cg = tid % CG;
    const int rg = tid / CG;

    float4 bias4 = make_float4(0.f, 0.f, 0.f, 0.f);
    if (bias) bias4 = ld4(bias + cg * 4);

    for (int base = blockIdx.x * ROWS; base < nrows; base += gridDim.x * ROWS) {
        __syncthreads();
        constexpr int NV = ROWS * K / 4;
        for (int i = tid; i < NV; i += 256) {
            int r = i / (K / 4), c = i % (K / 4);
            int gr = base + r;
            float4 v = make_float4(0.f, 0.f, 0.f, 0.f);
            if (gr < nrows) v = ld4(in + (size_t)gr * K + c * 4);
            st4(&Xl[r][c * 4], v);
        }

        float4 acc[RPT];
#pragma unroll
        for (int r = 0; r < RPT; ++r) acc[r] = bias4;

        for (int kh = 0; kh < K; kh += KH) {
            __syncthreads();
            constexpr int WV = KH * M / 4;
            for (int i = tid; i < WV; i += 256) {
                int kk = i / (M / 4), c = i % (M / 4);
                st4(&Wl[kk][c * 4], ld4(W + (size_t)(kh + kk) * M + c * 4));
            }
            __syncthreads();
#pragma unroll 4
            for (int kk = 0; kk < KH; ++kk) {
                float4 w4 = ld4(&Wl[kk][cg * 4]);
#pragma unroll
                for (int r = 0; r < RPT; ++r) {
                    float xv = Xl[rg * RPT + r][kh + kk];
                    acc[r].x = fmaf(xv, w4.x, acc[r].x);
                    acc[r].y = fmaf(xv, w4.y, acc[r].y);
                    acc[r].z = fmaf(xv, w4.z, acc[r].z);
                    acc[r].w = fmaf(xv, w4.w, acc[r].w);
                }
            }
        }
#pragma unroll
        for (int r = 0; r < RPT; ++r) {
            int gr = base + rg * RPT + r;
            if (gr < nrows) {
                if (BF16OUT) {
                    uint2 pk;
                    pk.x = pack2(acc[r].x, acc[r].y);
                    pk.y = pack2(acc[r].z, acc[r].w);
                    *reinterpret_cast<uint2*>((ushortT*)outp + (size_t)gr * M + cg * 4) = pk;
                } else {
                    st4((float*)outp + (size_t)gr * M + cg * 4, acc[r]);
                }
            }
        }
    }
}

// ---------------- launch ----------------

extern "C" void kernel_launch(void* const* d_in, const int* in_sizes, int n_in,
                              void* d_out, int out_size, void* d_ws, size_t ws_size,
                              hipStream_t stream) {
    const float* x   = (const float*)d_in[0];
    const int* eidx  = (const int*)d_in[1];
    const float* W1  = (const float*)d_in[2];
    const float* b1  = (const float*)d_in[3];
    const float* W2  = (const float*)d_in[4];
    const float* b2  = (const float*)d_in[5];
    const float* W3  = (const float*)d_in[6];
    const float* b3  = (const float*)d_in[7];
    const float* g1  = (const float*)d_in[8];
    const float* be1 = (const float*)d_in[9];
    const float* g2  = (const float*)d_in[10];
    const float* be2 = (const float*)d_in[11];
    const float* Ws1 = (const float*)d_in[12];
    const float* bs1 = (const float*)d_in[13];
    const float* Ws2 = (const float*)d_in[14];
    const float* bs2 = (const float*)d_in[15];
    float* out = (float*)d_out;

    const int N = in_sizes[0] / 64;
    const int E = in_sizes[1] / 2;
    const int* esrc = eidx;
    const int* edst = eidx + E;

    char* p = (char*)d_ws;
    auto alloc = [&](size_t bytes) -> char* {
        char* q = p;
        p += (bytes + 255) & ~(size_t)255;
        return q;
    };
    float* S      = (float*)alloc((size_t)N * 128 * 4);  // skip1, later X2
    float* X2     = S;
    float* X1     = (float*)alloc((size_t)N * 128 * 4);
    ushortT* x16  = (ushortT*)alloc((size_t)N * 64 * 2);
    ushortT* X1_16  = (ushortT*)alloc((size_t)N * 128 * 2);
    ushortT* HW3_16 = (ushortT*)alloc((size_t)N * 64 * 2);
    uint2* csr    = (uint2*)alloc((size_t)E * 8);
    int* counts   = (int*)alloc((size_t)N * 4);
    int* offsets  = (int*)alloc((size_t)N * 4);
    int* cursor   = (int*)alloc((size_t)N * 4);
    float* dinv   = (float*)alloc((size_t)N * 4);
    const int NB = (N + 511) / 512;
    int* bsum     = (int*)alloc((size_t)NB * 4);

    const int gN256 = (N + 255) / 256;
    const int gE256 = (E + 255) / 256;

    // ---- CSR build ----
    k_zero_i32<<<gN256, 256, 0, stream>>>(counts, N);
    k_count<<<gE256, 256, 0, stream>>>(edst, counts, E);
    k_dinv<<<gN256, 256, 0, stream>>>(counts, dinv, N);
    k_scan1<<<NB, 512, 0, stream>>>(counts, bsum, N);
    k_scan2<<<1, 512, 0, stream>>>(bsum, NB);
    k_scan3<<<NB, 512, 0, stream>>>(counts, bsum, offsets, cursor, N);
    k_fill<<<gE256, 256, 0, stream>>>(esrc, edst, dinv, cursor, csr, E);
    // cursor[i] = row end

    // ---- layer 1 ----
    k_cvt_bf16<<<(N * 16 + 255) / 256, 256, 0, stream>>>(x, x16, N * 16);             // x -> bf16
    gemm_small<64, 128, false><<<(N + 31) / 32, 256, 0, stream>>>(x, Ws1, bs1, S, N); // skip1
    k_agg_gemm_ln<64><<<(N + 31) / 32, 256, 0, stream>>>(x16, csr, offsets, cursor, dinv,
                                                         W1, b1, g1, be1, S,
                                                         X1, X1_16, N);               // X1 = x1 (+bf16)

    // ---- layer 2 ----
    k_agg_gemm_ln<128><<<(N + 15) / 16, 256, 0, stream>>>(X1_16, csr, offsets, cursor, dinv,
                                                          W2, b2, g2, be2, X1,
                                                          X2, (ushortT*)nullptr, N);  // X2 = x2

    // ---- layer 3 ----
    gemm_small<128, 64, false><<<(N + 63) / 64, 256, 0, stream>>>(X1, Ws2, bs2, out, N);      // skip3
    gemm_small<128, 64, true><<<(N + 63) / 64, 256, 0, stream>>>(X2, W3, nullptr, HW3_16, N); // hw3 bf16
    k_final<<<(N + 31) / 32, 256, 0, stream>>>(HW3_16, offsets, cursor, csr,
                                               dinv, b3, out, N);                     // out += A~ hw3 + b3
}

// Round 7
// 557.344 us; speedup vs baseline: 1.1369x; 1.1369x over previous
//
#include <hip/hip_runtime.h>

#define LN_EPS 1e-5f

typedef unsigned short ushortT;

__device__ __forceinline__ float4 ld4(const float* p) { return *reinterpret_cast<const float4*>(p); }
__device__ __forceinline__ void st4(float* p, float4 v) { *reinterpret_cast<float4*>(p) = v; }
__device__ __forceinline__ float bf2f(unsigned u) { return __uint_as_float(u << 16); }
__device__ __forceinline__ unsigned short f2bf(float f) {
    unsigned u = __float_as_uint(f);
    u += 0x7fffu + ((u >> 16) & 1u);   // round to nearest even
    return (unsigned short)(u >> 16);
}
__device__ __forceinline__ unsigned pack2(float a, float b) {
    return (unsigned)f2bf(a) | ((unsigned)f2bf(b) << 16);
}

// ---------------- CSR build ----------------

__global__ __launch_bounds__(256) void k_zero_i32(int* __restrict__ p, int n) {
    int i = blockIdx.x * 256 + threadIdx.x;
    if (i < n) p[i] = 0;
}

__global__ __launch_bounds__(256) void k_count(const int* __restrict__ dst, int* __restrict__ counts, int E) {
    int i = blockIdx.x * 256 + threadIdx.x;
    if (i < E) atomicAdd(&counts[dst[i]], 1);
}

__global__ __launch_bounds__(256) void k_dinv(const int* __restrict__ counts, float* __restrict__ dinv, int n) {
    int i = blockIdx.x * 256 + threadIdx.x;
    if (i < n) dinv[i] = rsqrtf((float)(counts[i] + 1));   // +1 = self loop
}

__global__ __launch_bounds__(512) void k_scan1(const int* __restrict__ counts, int* __restrict__ bsum, int n) {
    __shared__ int s[512];
    int idx = blockIdx.x * 512 + threadIdx.x;
    s[threadIdx.x] = (idx < n) ? counts[idx] : 0;
    __syncthreads();
    for (int d = 256; d > 0; d >>= 1) {
        if (threadIdx.x < d) s[threadIdx.x] += s[threadIdx.x + d];
        __syncthreads();
    }
    if (threadIdx.x == 0) bsum[blockIdx.x] = s[0];
}

// parallel single-block exclusive scan over block sums (nb <= 512)
__global__ __launch_bounds__(512) void k_scan2(int* __restrict__ bsum, int nb) {
    __shared__ int s[512];
    int t = threadIdx.x;
    int v = (t < nb) ? bsum[t] : 0;
    s[t] = v;
    __syncthreads();
    for (int d = 1; d < 512; d <<= 1) {
        int tv = (t >= d) ? s[t - d] : 0;
        __syncthreads();
        s[t] += tv;
        __syncthreads();
    }
    if (t < nb) bsum[t] = s[t] - v;   // exclusive
}

__global__ __launch_bounds__(512) void k_scan3(const int* __restrict__ counts, const int* __restrict__ bsum,
                                               int* __restrict__ offsets, int* __restrict__ cursor, int n) {
    __shared__ int s[512];
    int tid = threadIdx.x;
    int idx = blockIdx.x * 512 + tid;
    int v = (idx < n) ? counts[idx] : 0;
    s[tid] = v;
    __syncthreads();
    for (int d = 1; d < 512; d <<= 1) {
        int t = (tid >= d) ? s[tid - d] : 0;
        __syncthreads();
        s[tid] += t;
        __syncthreads();
    }
    if (idx < n) {
        int ex = s[tid] - v + bsum[blockIdx.x];
        offsets[idx] = ex;
        cursor[idx] = ex;
    }
}

// one fused 8B scattered store per edge: {src, bits(dinv[src])}
__global__ __launch_bounds__(256) void k_fill(const int* __restrict__ src, const int* __restrict__ dst,
                                              const float* __restrict__ dinv, int* __restrict__ cursor,
                                              uint2* __restrict__ csr, int E) {
    int i = blockIdx.x * 256 + threadIdx.x;
    if (i < E) {
        int d = dst[i], s = src[i];
        int p = atomicAdd(&cursor[d], 1);
        uint2 v;
        v.x = (unsigned)s;
        v.y = __float_as_uint(dinv[s]);
        csr[p] = v;
    }
}

// ---------------- f32 -> bf16 convert ----------------

__global__ __launch_bounds__(256) void k_cvt_bf16(const float* __restrict__ in, ushortT* __restrict__ o, int n4) {
    int i = blockIdx.x * 256 + threadIdx.x;
    if (i < n4) {
        float4 v = ld4(in + (size_t)i * 4);
        uint2 pk;
        pk.x = pack2(v.x, v.y);
        pk.y = pack2(v.z, v.w);
        *reinterpret_cast<uint2*>(o + (size_t)i * 4) = pk;
    }
}

// ---------------- fused: LDS-aggregate -> GEMM -> bias/LN/ReLU/skip ----------------
// 512 threads; KH=32 W-staging keeps LDS ~33KB -> 4 blocks/CU (32 waves).
// Phase A: G=K/8 lanes per node gather bf16 rows (4-deep unroll), f32 acc -> LDS Xl.
// Phase B: Xl[NODES][K] @ W[K][128] with LN epilogue.

template <int K, int MINW>
__global__ __launch_bounds__(512, MINW) void k_agg_gemm_ln(
        const ushortT* __restrict__ t16, const uint2* __restrict__ csr,
        const int* __restrict__ rs, const int* __restrict__ re,
        const float* __restrict__ dinv,
        const float* __restrict__ W, const float* __restrict__ bias,
        const float* __restrict__ g, const float* __restrict__ be,
        const float* __restrict__ skip,
        float* __restrict__ out32, ushortT* __restrict__ out16, int n) {
    constexpr int M = 128;
    constexpr int G = K / 8;          // lanes per node (agg phase)
    constexpr int NODES = 512 / G;    // 64 (K=64) / 32 (K=128)
    constexpr int RPT = NODES / 16;   // 4 / 2
    constexpr int KH = 32;
    constexpr int KP = K + 8;         // row pad keeps 16B alignment

    __shared__ float Wl[KH][M];
    __shared__ float Xl[NODES][KP];

    const int tid = threadIdx.x;

    // ---- Phase A: aggregate into LDS ----
    {
        const int grp = tid / G;
        const int sub = tid % G;
        const int node = blockIdx.x * NODES + grp;
        float a[8];
#pragma unroll
        for (int i = 0; i < 8; ++i) a[i] = 0.f;

        if (node < n) {
            const float di = dinv[node];
            const ushortT* base = t16 + sub * 8;
            const int p0 = rs[node], p1 = re[node];

            auto acc8 = [&](uint4 v, float w) {
                a[0] = fmaf(bf2f(v.x & 0xffffu), w, a[0]); a[1] = fmaf(bf2f(v.x >> 16), w, a[1]);
                a[2] = fmaf(bf2f(v.y & 0xffffu), w, a[2]); a[3] = fmaf(bf2f(v.y >> 16), w, a[3]);
                a[4] = fmaf(bf2f(v.z & 0xffffu), w, a[4]); a[5] = fmaf(bf2f(v.z >> 16), w, a[5]);
                a[6] = fmaf(bf2f(v.w & 0xffffu), w, a[6]); a[7] = fmaf(bf2f(v.w >> 16), w, a[7]);
            };

            int p = p0;
            for (; p + 4 <= p1; p += 4) {
                uint2 e0 = csr[p], e1 = csr[p + 1], e2 = csr[p + 2], e3 = csr[p + 3];
                uint4 v0 = *reinterpret_cast<const uint4*>(base + (size_t)e0.x * K);
                uint4 v1 = *reinterpret_cast<const uint4*>(base + (size_t)e1.x * K);
                uint4 v2 = *reinterpret_cast<const uint4*>(base + (size_t)e2.x * K);
                uint4 v3 = *reinterpret_cast<const uint4*>(base + (size_t)e3.x * K);
                acc8(v0, __uint_as_float(e0.y) * di);
                acc8(v1, __uint_as_float(e1.y) * di);
                acc8(v2, __uint_as_float(e2.y) * di);
                acc8(v3, __uint_as_float(e3.y) * di);
            }
            for (; p < p1; ++p) {
                uint2 e0 = csr[p];
                uint4 v0 = *reinterpret_cast<const uint4*>(base + (size_t)e0.x * K);
                acc8(v0, __uint_as_float(e0.y) * di);
            }
            {   // self loop
                uint4 v = *reinterpret_cast<const uint4*>(base + (size_t)node * K);
                acc8(v, di * di);
            }
        }
        st4(&Xl[grp][sub * 8], make_float4(a[0], a[1], a[2], a[3]));
        st4(&Xl[grp][sub * 8 + 4], make_float4(a[4], a[5], a[6], a[7]));
    }

    // ---- Phase B: GEMM + LN epilogue ----
    const int cg = tid & 31;
    const int rg = tid >> 5;   // 0..15
    const float4 bias4 = ld4(bias + cg * 4);

    float4 acc[RPT];
#pragma unroll
    for (int r = 0; r < RPT; ++r) acc[r] = bias4;

    for (int kh = 0; kh < K; kh += KH) {
        __syncthreads();   // Xl ready (1st iter) / Wl reuse safe (later)
        for (int i = tid; i < KH * M / 4; i += 512) {
            int kk = i / (M / 4), c = i % (M / 4);
            st4(&Wl[kk][c * 4], ld4(W + (size_t)(kh + kk) * M + c * 4));
        }
        __syncthreads();
#pragma unroll 4
        for (int kk = 0; kk < KH; ++kk) {
            float4 w4 = ld4(&Wl[kk][cg * 4]);
#pragma unroll
            for (int r = 0; r < RPT; ++r) {
                float xv = Xl[rg * RPT + r][kh + kk];
                acc[r].x = fmaf(xv, w4.x, acc[r].x);
                acc[r].y = fmaf(xv, w4.y, acc[r].y);
                acc[r].z = fmaf(xv, w4.z, acc[r].z);
                acc[r].w = fmaf(xv, w4.w, acc[r].w);
            }
        }
    }

    const float4 g4 = ld4(g + cg * 4);
    const float4 be4 = ld4(be + cg * 4);
#pragma unroll
    for (int r = 0; r < RPT; ++r) {
        int gr = blockIdx.x * NODES + rg * RPT + r;
        if (gr >= n) continue;
        float4 a = acc[r];
        float sum = a.x + a.y + a.z + a.w;
#pragma unroll
        for (int m = 16; m > 0; m >>= 1) sum += __shfl_xor(sum, m, 32);
        const float mean = sum * (1.f / 128.f);
        float dx = a.x - mean, dy = a.y - mean, dz = a.z - mean, dw = a.w - mean;
        float sq = dx * dx + dy * dy + dz * dz + dw * dw;
#pragma unroll
        for (int m = 16; m > 0; m >>= 1) sq += __shfl_xor(sq, m, 32);
        const float rstd = rsqrtf(sq * (1.f / 128.f) + LN_EPS);
        float4 s4 = ld4(skip + (size_t)gr * 128 + cg * 4);
        float4 y;
        y.x = fmaxf(fmaf(dx * rstd, g4.x, be4.x), 0.f) + s4.x;
        y.y = fmaxf(fmaf(dy * rstd, g4.y, be4.y), 0.f) + s4.y;
        y.z = fmaxf(fmaf(dz * rstd, g4.z, be4.z), 0.f) + s4.z;
        y.w = fmaxf(fmaf(dw * rstd, g4.w, be4.w), 0.f) + s4.w;
        st4(out32 + (size_t)gr * 128 + cg * 4, y);
        if (out16) {
            uint2 pk;
            pk.x = pack2(y.x, y.y);
            pk.y = pack2(y.z, y.w);
            *reinterpret_cast<uint2*>(out16 + (size_t)gr * 128 + cg * 4) = pk;
        }
    }
}

// ---------------- final: out += Agg(hw3_16) + b3 (out pre-filled with skip3) ----------------

__global__ __launch_bounds__(256) void k_final(const ushortT* __restrict__ t16,
                                               const int* __restrict__ rs, const int* __restrict__ re,
                                               const uint2* __restrict__ csr,
                                               const float* __restrict__ dinv, const float* __restrict__ bias,
                                               float* __restrict__ out, int n) {
    constexpr int C = 64, G = 8, NPB = 32;
    const int grp = threadIdx.x / G;
    const int sub = threadIdx.x % G;
    const int node = blockIdx.x * NPB + grp;
    if (node >= n) return;
    const float di = dinv[node];
    float a[8];
#pragma unroll
    for (int i = 0; i < 8; ++i) a[i] = 0.f;
    const ushortT* base = t16 + sub * 8;
    const int p0 = rs[node], p1 = re[node];

    auto acc8 = [&](uint4 v, float w) {
        a[0] = fmaf(bf2f(v.x & 0xffffu), w, a[0]); a[1] = fmaf(bf2f(v.x >> 16), w, a[1]);
        a[2] = fmaf(bf2f(v.y & 0xffffu), w, a[2]); a[3] = fmaf(bf2f(v.y >> 16), w, a[3]);
        a[4] = fmaf(bf2f(v.z & 0xffffu), w, a[4]); a[5] = fmaf(bf2f(v.z >> 16), w, a[5]);
        a[6] = fmaf(bf2f(v.w & 0xffffu), w, a[6]); a[7] = fmaf(bf2f(v.w >> 16), w, a[7]);
    };

    int p = p0;
    for (; p + 4 <= p1; p += 4) {
        uint2 e0 = csr[p], e1 = csr[p + 1], e2 = csr[p + 2], e3 = csr[p + 3];
        uint4 v0 = *reinterpret_cast<const uint4*>(base + (size_t)e0.x * C);
        uint4 v1 = *reinterpret_cast<const uint4*>(base + (size_t)e1.x * C);
        uint4 v2 = *reinterpret_cast<const uint4*>(base + (size_t)e2.x * C);
        uint4 v3 = *reinterpret_cast<const uint4*>(base + (size_t)e3.x * C);
        acc8(v0, __uint_as_float(e0.y) * di);
        acc8(v1, __uint_as_float(e1.y) * di);
        acc8(v2, __uint_as_float(e2.y) * di);
        acc8(v3, __uint_as_float(e3.y) * di);
    }
    for (; p < p1; ++p) {
        uint2 e0 = csr[p];
        uint4 v0 = *reinterpret_cast<const uint4*>(base + (size_t)e0.x * C);
        acc8(v0, __uint_as_float(e0.y) * di);
    }
    {
        uint4 v = *reinterpret_cast<const uint4*>(base + (size_t)node * C);
        acc8(v, di * di);
    }
    float* o = out + (size_t)node * 64 + sub * 8;
    const float* b = bias + sub * 8;
    float4 c0 = ld4(o), c1 = ld4(o + 4);
    float4 b0 = ld4(b), b1 = ld4(b + 4);
    st4(o, make_float4(c0.x + a[0] + b0.x, c0.y + a[1] + b0.y,
                       c0.z + a[2] + b0.z, c0.w + a[3] + b0.w));
    st4(o + 4, make_float4(c1.x + a[4] + b1.x, c1.y + a[5] + b1.y,
                           c1.z + a[6] + b1.z, c1.w + a[7] + b1.w));
}

// ---------------- small-K GEMM: out[N,M] = in[N,K] @ W[K,M] (+bias); f32 or bf16 out ----------------
// KH=32 keeps LDS ~25KB -> 6 blocks/CU.

template <int K, int M, bool BF16OUT>
__global__ __launch_bounds__(256) void gemm_small(const float* __restrict__ in, const float* __restrict__ W,
                                                  const float* __restrict__ bias, void* __restrict__ outp,
                                                  int nrows) {
    constexpr int CG = M / 4;
    constexpr int RG = 256 / CG;
    constexpr int RPT = (M == 128) ? 4 : 2;
    constexpr int ROWS = RG * RPT;    // 32 both
    constexpr int KH = 32;
    constexpr int KP = K + 4;

    __shared__ float Wl[KH][M];
    __shared__ float Xl[ROWS][KP];

    const int tid = threadIdx.x;
    const int cg = tid % CG;
    const int rg = tid / CG;

    float4 bias4 = make_float4(0.f, 0.f, 0.f, 0.f);
    if (bias) bias4 = ld4(bias + cg * 4);

    for (int base = blockIdx.x * ROWS; base < nrows; base += gridDim.x * ROWS) {
        __syncthreads();
        constexpr int NV = ROWS * K / 4;
        for (int i = tid; i < NV; i += 256) {
            int r = i / (K / 4), c = i % (K / 4);
            int gr = base + r;
            float4 v = make_float4(0.f, 0.f, 0.f, 0.f);
            if (gr < nrows) v = ld4(in + (size_t)gr * K + c * 4);
            st4(&Xl[r][c * 4], v);
        }

        float4 acc[RPT];
#pragma unroll
        for (int r = 0; r < RPT; ++r) acc[r] = bias4;

        for (int kh = 0; kh < K; kh += KH) {
            __syncthreads();
            constexpr int WV = KH * M / 4;
            for (int i = tid; i < WV; i += 256) {
                int kk = i / (M / 4), c = i % (M / 4);
                st4(&Wl[kk][c * 4], ld4(W + (size_t)(kh + kk) * M + c * 4));
            }
            __syncthreads();
#pragma unroll 4
            for (int kk = 0; kk < KH; ++kk) {
                float4 w4 = ld4(&Wl[kk][cg * 4]);
#pragma unroll
                for (int r = 0; r < RPT; ++r) {
                    float xv = Xl[rg * RPT + r][kh + kk];
                    acc[r].x = fmaf(xv, w4.x, acc[r].x);
                    acc[r].y = fmaf(xv, w4.y, acc[r].y);
                    acc[r].z = fmaf(xv, w4.z, acc[r].z);
                    acc[r].w = fmaf(xv, w4.w, acc[r].w);
                }
            }
        }
#pragma unroll
        for (int r = 0; r < RPT; ++r) {
            int gr = base + rg * RPT + r;
            if (gr < nrows) {
                if (BF16OUT) {
                    uint2 pk;
                    pk.x = pack2(acc[r].x, acc[r].y);
                    pk.y = pack2(acc[r].z, acc[r].w);
                    *reinterpret_cast<uint2*>((ushortT*)outp + (size_t)gr * M + cg * 4) = pk;
                } else {
                    st4((float*)outp + (size_t)gr * M + cg * 4, acc[r]);
                }
            }
        }
    }
}

// ---------------- launch ----------------

extern "C" void kernel_launch(void* const* d_in, const int* in_sizes, int n_in,
                              void* d_out, int out_size, void* d_ws, size_t ws_size,
                              hipStream_t stream) {
    const float* x   = (const float*)d_in[0];
    const int* eidx  = (const int*)d_in[1];
    const float* W1  = (const float*)d_in[2];
    const float* b1  = (const float*)d_in[3];
    const float* W2  = (const float*)d_in[4];
    const float* b2  = (const float*)d_in[5];
    const float* W3  = (const float*)d_in[6];
    const float* b3  = (const float*)d_in[7];
    const float* g1  = (const float*)d_in[8];
    const float* be1 = (const float*)d_in[9];
    const float* g2  = (const float*)d_in[10];
    const float* be2 = (const float*)d_in[11];
    const float* Ws1 = (const float*)d_in[12];
    const float* bs1 = (const float*)d_in[13];
    const float* Ws2 = (const float*)d_in[14];
    const float* bs2 = (const float*)d_in[15];
    float* out = (float*)d_out;

    const int N = in_sizes[0] / 64;
    const int E = in_sizes[1] / 2;
    const int* esrc = eidx;
    const int* edst = eidx + E;

    char* p = (char*)d_ws;
    auto alloc = [&](size_t bytes) -> char* {
        char* q = p;
        p += (bytes + 255) & ~(size_t)255;
        return q;
    };
    float* S      = (float*)alloc((size_t)N * 128 * 4);  // skip1, later X2
    float* X2     = S;
    float* X1     = (float*)alloc((size_t)N * 128 * 4);
    ushortT* x16  = (ushortT*)alloc((size_t)N * 64 * 2);
    ushortT* X1_16  = (ushortT*)alloc((size_t)N * 128 * 2);
    ushortT* HW3_16 = (ushortT*)alloc((size_t)N * 64 * 2);
    uint2* csr    = (uint2*)alloc((size_t)E * 8);
    int* counts   = (int*)alloc((size_t)N * 4);
    int* offsets  = (int*)alloc((size_t)N * 4);
    int* cursor   = (int*)alloc((size_t)N * 4);
    float* dinv   = (float*)alloc((size_t)N * 4);
    const int NB = (N + 511) / 512;
    int* bsum     = (int*)alloc((size_t)NB * 4);

    const int gN256 = (N + 255) / 256;
    const int gE256 = (E + 255) / 256;

    // ---- CSR build ----
    k_zero_i32<<<gN256, 256, 0, stream>>>(counts, N);
    k_count<<<gE256, 256, 0, stream>>>(edst, counts, E);
    k_dinv<<<gN256, 256, 0, stream>>>(counts, dinv, N);
    k_scan1<<<NB, 512, 0, stream>>>(counts, bsum, N);
    k_scan2<<<1, 512, 0, stream>>>(bsum, NB);
    k_scan3<<<NB, 512, 0, stream>>>(counts, bsum, offsets, cursor, N);
    k_fill<<<gE256, 256, 0, stream>>>(esrc, edst, dinv, cursor, csr, E);
    // cursor[i] = row end

    // ---- layer 1 ----
    k_cvt_bf16<<<(N * 16 + 255) / 256, 256, 0, stream>>>(x, x16, N * 16);             // x -> bf16
    gemm_small<64, 128, false><<<(N + 31) / 32, 256, 0, stream>>>(x, Ws1, bs1, S, N); // skip1
    k_agg_gemm_ln<64, 6><<<(N + 63) / 64, 512, 0, stream>>>(x16, csr, offsets, cursor, dinv,
                                                            W1, b1, g1, be1, S,
                                                            X1, X1_16, N);            // X1 = x1 (+bf16)

    // ---- layer 2 ----
    k_agg_gemm_ln<128, 8><<<(N + 31) / 32, 512, 0, stream>>>(X1_16, csr, offsets, cursor, dinv,
                                                             W2, b2, g2, be2, X1,
                                                             X2, (ushortT*)nullptr, N); // X2 = x2

    // ---- layer 3 ----
    gemm_small<128, 64, false><<<(N + 31) / 32, 256, 0, stream>>>(X1, Ws2, bs2, out, N);      // skip3
    gemm_small<128, 64, true><<<(N + 31) / 32, 256, 0, stream>>>(X2, W3, nullptr, HW3_16, N); // hw3 bf16
    k_final<<<(N + 31) / 32, 256, 0, stream>>>(HW3_16, offsets, cursor, csr,
                                               dinv, b3, out, N);                     // out += A~ hw3 + b3
}